// Round 7
// baseline (82024.750 us; speedup 1.0000x reference)
//
#include <hip/hip_runtime.h>
#include <hip/hip_cooperative_groups.h>

namespace cg = cooperative_groups;

#define Tn 512
#define NBLK 256
#define NTHR 512

__device__ __forceinline__ float sigf(float v){ return 1.0f/(1.0f+__expf(-v)); }
__device__ __forceinline__ float tanhfast(float v){
    float ax=fabsf(v); float e=__expf(-2.0f*ax);
    float t=(1.0f-e)/(1.0f+e); return copysignf(t,v);
}
__device__ __forceinline__ float dot4(float4 a, float4 b){
    return a.x*b.x + a.y*b.y + a.z*b.z + a.w*b.w;
}

// ws layout (float offsets) — round-2-proven 786432-float footprint:
//   hm32 : 2 x [128][1024] f32 @ 0        (h_m, [b][g*256+h], buf p = p*131072)
//   hj32 : 2 x [128][1024] f32 @ 262144   (h_j, [b][j])
//   ng32 : 2 x [128][1024] f32 @ 524288   (newgates, [b][g*256+h])
// state(t) in buf t&1 ; t=-1 zeros live in buf 1.
//
// BISECTION ROUND: same decomposition/exchange/state as rounds 4-6, but the
// dot engines are scalar fp32 (no MFMA, no bf16). Output positions per lane
// mirror the MFMA claimed mapping: (lm, ln) = (q4+r, r16).

__launch_bounds__(NTHR, 2)
__global__ void mgrn_k(const float* __restrict__ x,
                       const float* __restrict__ w_ih,
                       const float* __restrict__ w_hh,
                       const float* __restrict__ b_ih,
                       const float* __restrict__ u_c,
                       const float* __restrict__ b_c,
                       const float* __restrict__ w_z,
                       const float* __restrict__ u_z,
                       const float* __restrict__ b_z,
                       float* __restrict__ out,
                       float* __restrict__ ws,
                       int s_lo, int s_hi, int coop)
{
    cg::grid_group grid = cg::this_grid();
    __shared__ float smem[2048];   // 8 KiB acc-exchange

    float* hm32 = ws;
    float* hj32 = ws + 262144;
    float* ng32 = ws + 524288;

    const int tid  = threadIdx.x;
    const int lane = tid & 63;
    const int wv   = tid >> 6;          // 0..7
    const int tb   = wv & 3;            // b-tile 0..3
    const int hf   = wv >> 2;           // 0: r/c side, 1: z side
    const int r16  = lane & 15;
    const int q4   = (lane >> 4) * 4;
    const int wg   = blockIdx.x;
    const bool isMarg = (wg < 128);

    if (coop) {   // zero t=-1 state (buf 1) of hm and hj
        int gidx = wg * NTHR + tid;     // exactly [0, 131072)
        ws[131072 + gidx] = 0.0f;       // hm32 buf1
        ws[393216 + gidx] = 0.0f;       // hj32 buf1
        grid.sync();
    }

    if (isMarg) {
        // ============ MARGINAL: block = 16 h-rows x 64 batch ============
        const int c  = wg >> 1;               // 0..63
        const int bh = wg & 1;
        const int g  = c >> 4;
        const int h0 = (c & 15) * 16;
        const int bbo = bh*64 + tb*16 + r16;  // this lane's batch

        const float* wih_g = w_ih + (size_t)g * 768 * 64;
        const float* whh_g = w_hh + (size_t)g * 768 * 256;
        const int gA = hf ? 256 : 0;          // accA gate block: r (hf0) / z (hf1)

        float br_[4], bz_[4], bn_[4];
        #pragma unroll
        for (int r = 0; r < 4; ++r) {
            int hh = h0 + q4 + r;
            br_[r] = b_ih[g*768 + hh];
            bz_[r] = b_ih[g*768 + 256 + hh];
            bn_[r] = b_ih[g*768 + 512 + hh];
        }

        for (int s = s_lo; s <= s_hi; ++s) {
            if (s < Tn) {
                const int p0 = s & 1, p1 = (s+1) & 1;
                float accA[4] = {0.f,0.f,0.f,0.f};   // r (hf0) or z (hf1), full K
                float accB[4] = {0.f,0.f,0.f,0.f};   // i_n (hf0) or h_n (hf1)
                const float* xrow = x + ((size_t)s*128 + bbo)*256 + g*64;
                const float* hrow = hm32 + p1*131072 + bbo*1024 + g*256;

                // x-part K=64
                for (int k4 = 0; k4 < 16; ++k4) {
                    float4 xv = *(const float4*)(xrow + k4*4);
                    #pragma unroll
                    for (int r = 0; r < 4; ++r) {
                        float4 wv = *(const float4*)(wih_g + (size_t)(gA + h0 + q4 + r)*64 + k4*4);
                        accA[r] += dot4(wv, xv);
                    }
                    if (hf == 0) {
                        #pragma unroll
                        for (int r = 0; r < 4; ++r) {
                            float4 wn = *(const float4*)(wih_g + (size_t)(512 + h0 + q4 + r)*64 + k4*4);
                            accB[r] += dot4(wn, xv);
                        }
                    }
                }
                // h-part K=256
                for (int k4 = 0; k4 < 64; ++k4) {
                    float4 hv = *(const float4*)(hrow + k4*4);
                    #pragma unroll
                    for (int r = 0; r < 4; ++r) {
                        float4 wv = *(const float4*)(whh_g + (size_t)(gA + h0 + q4 + r)*256 + k4*4);
                        accA[r] += dot4(wv, hv);
                    }
                    if (hf == 1) {
                        #pragma unroll
                        for (int r = 0; r < 4; ++r) {
                            float4 wn = *(const float4*)(whh_g + (size_t)(512 + h0 + q4 + r)*256 + k4*4);
                            accB[r] += dot4(wn, hv);
                        }
                    }
                }

                if (hf == 1) {
                    #pragma unroll
                    for (int r = 0; r < 4; ++r) {
                        int idx = (q4 + r)*16 + r16;
                        smem[(tb*2 + 0)*256 + idx] = accA[r];   // z partial
                        smem[(tb*2 + 1)*256 + idx] = accB[r];   // hn partial
                    }
                }
                __syncthreads();
                if (hf == 0) {
                    #pragma unroll
                    for (int r = 0; r < 4; ++r) {
                        int idx = (q4 + r)*16 + r16;
                        int kk  = g*256 + h0 + q4 + r;
                        float zacc  = smem[(tb*2 + 0)*256 + idx];
                        float hnacc = smem[(tb*2 + 1)*256 + idx];
                        float rg = sigf(accA[r] + br_[r]);
                        float zg = sigf(zacc + bz_[r]);
                        float n  = tanhfast(accB[r] + bn_[r] + rg * hnacc);
                        float hmo = hm32[p1*131072 + bbo*1024 + kk];
                        float hnew = n + zg * (hmo - n);
                        hm32[p0*131072 + bbo*1024 + kk] = hnew;
                        ng32[p0*131072 + bbo*1024 + kk] = n;
                    }
                }
            }
            if (coop) grid.sync();
        }
    } else {
        // ============ JOINT: block = 16 j-rows x 64 batch, 1 step behind ====
        const int wg2 = wg - 128;
        const int j0  = (wg2 >> 1) * 16;
        const int bh  = wg2 & 1;
        const int bbo = bh*64 + tb*16 + r16;

        float bc_[4], bzj_[4];
        #pragma unroll
        for (int r = 0; r < 4; ++r) {
            int jj = j0 + q4 + r;
            bc_[r]  = b_c[jj];
            bzj_[r] = b_z[jj];
        }

        for (int s = s_lo; s <= s_hi; ++s) {
            if (s >= 1) {
                const int u  = s - 1;
                const int p0 = u & 1, p1 = (u+1) & 1;
                float acc[4] = {0.f,0.f,0.f,0.f};

                if (hf == 0) {
                    // c-part: ng(u) . u_c rows, K=1024
                    const float* ngrow = ng32 + p0*131072 + bbo*1024;
                    for (int k4 = 0; k4 < 256; ++k4) {
                        float4 av = *(const float4*)(ngrow + k4*4);
                        #pragma unroll
                        for (int r = 0; r < 4; ++r) {
                            float4 wv = *(const float4*)(u_c + (size_t)(j0 + q4 + r)*1024 + k4*4);
                            acc[r] += dot4(wv, av);
                        }
                    }
                } else {
                    // z-part: h_j(u-1) . u_z rows, K=1024
                    const float* hjrow = hj32 + p1*131072 + bbo*1024;
                    for (int k4 = 0; k4 < 256; ++k4) {
                        float4 hv = *(const float4*)(hjrow + k4*4);
                        #pragma unroll
                        for (int r = 0; r < 4; ++r) {
                            float4 wv = *(const float4*)(u_z + (size_t)(j0 + q4 + r)*1024 + k4*4);
                            acc[r] += dot4(wv, hv);
                        }
                    }
                    // x-part of zj: K=256
                    const float* xrow = x + ((size_t)u*128 + bbo)*256;
                    for (int k4 = 0; k4 < 64; ++k4) {
                        float4 xv = *(const float4*)(xrow + k4*4);
                        #pragma unroll
                        for (int r = 0; r < 4; ++r) {
                            float4 wv = *(const float4*)(w_z + (size_t)(j0 + q4 + r)*256 + k4*4);
                            acc[r] += dot4(wv, xv);
                        }
                    }
                    #pragma unroll
                    for (int r = 0; r < 4; ++r) {
                        int idx = (q4 + r)*16 + r16;
                        smem[tb*256 + idx] = acc[r];            // zj partial
                    }
                }
                __syncthreads();
                if (hf == 0) {
                    #pragma unroll
                    for (int r = 0; r < 4; ++r) {
                        int idx = (q4 + r)*16 + r16;
                        int jj  = j0 + q4 + r;
                        float zacc = smem[tb*256 + idx];
                        float cg_  = tanhfast(acc[r] + bc_[r]);
                        float zj   = sigf(zacc + bzj_[r]);
                        float hjo  = hj32[p1*131072 + bbo*1024 + jj];
                        float hnew = cg_ + zj * (hjo - cg_);
                        hj32[p0*131072 + bbo*1024 + jj] = hnew;
                        if (u == Tn-1) out[(size_t)bbo*1024 + jj] = hnew;
                    }
                }
            }
            if (coop) grid.sync();
        }
    }
}

extern "C" void kernel_launch(void* const* d_in, const int* in_sizes, int n_in,
                              void* d_out, int out_size, void* d_ws, size_t ws_size,
                              hipStream_t stream) {
    const float* x    = (const float*)d_in[0];
    const float* w_ih = (const float*)d_in[1];
    const float* w_hh = (const float*)d_in[2];
    const float* b_ih = (const float*)d_in[3];
    const float* u_c  = (const float*)d_in[4];
    const float* b_c  = (const float*)d_in[5];
    const float* w_z  = (const float*)d_in[6];
    const float* u_z  = (const float*)d_in[7];
    const float* b_z  = (const float*)d_in[8];
    float* out = (float*)d_out;
    float* ws  = (float*)d_ws;

    int s_lo = 0, s_hi = Tn, coop = 1;
    void* args[] = {&x, &w_ih, &w_hh, &b_ih, &u_c, &b_c, &w_z, &u_z, &b_z,
                    &out, &ws, &s_lo, &s_hi, &coop};
    hipError_t e = hipLaunchCooperativeKernel((void*)mgrn_k, dim3(NBLK), dim3(NTHR),
                                              args, 0, stream);
    if (e != hipSuccess) {
        (void)hipGetLastError();   // clear sticky error
        hipMemsetAsync(ws, 0, (size_t)786432 * sizeof(float), stream);
        for (int s = 0; s <= Tn; ++s) {
            mgrn_k<<<dim3(NBLK), dim3(NTHR), 0, stream>>>(
                x, w_ih, w_hh, b_ih, u_c, b_c, w_z, u_z, b_z, out, ws, s, s, 0);
        }
    }
}

// Round 8
// 47856.155 us; speedup vs baseline: 1.7140x; 1.7140x over previous
//
#include <hip/hip_runtime.h>
#include <hip/hip_cooperative_groups.h>

namespace cg = cooperative_groups;

#define Tn 512
#define NBLK 256
#define NTHR 512

// LDS layout (floats), dynamic:
//  JOINT : uc_s [16][1028] @0 ; uz_s [16][1028] @16448 ; wz_s [16][260] @32896 ;
//          exch [2048] @37056  -> total 39104 floats = 156416 B
//  MARG  : wih_s [48][68] @0 ; whh_s [48][260] @3264 ; exch [2048] @15744
#define LDS_BYTES 156416
#define JT_UZ 16448
#define JT_WZ 32896
#define JT_EX 37056
#define MG_WHH 3264
#define MG_EX 15744

__device__ __forceinline__ float sigf(float v){ return 1.0f/(1.0f+__expf(-v)); }
__device__ __forceinline__ float tanhfast(float v){
    float ax=fabsf(v); float e=__expf(-2.0f*ax);
    float t=(1.0f-e)/(1.0f+e); return copysignf(t,v);
}
__device__ __forceinline__ float dot4(float4 a, float4 b){
    return a.x*b.x + a.y*b.y + a.z*b.z + a.w*b.w;
}

// ws layout (float offsets) — proven 786432-float footprint:
//   hm32 : 2 x [128][1024] f32 @ 0        (h_m, [b][g*256+h], buf p = p*131072)
//   hj32 : 2 x [128][1024] f32 @ 262144   (h_j, [b][j])
//   ng32 : 2 x [128][1024] f32 @ 524288   (newgates, [b][g*256+h])
// state(t) in buf t&1 ; t=-1 zeros live in buf 1.

__launch_bounds__(NTHR, 2)
__global__ void mgrn_k(const float* __restrict__ x,
                       const float* __restrict__ w_ih,
                       const float* __restrict__ w_hh,
                       const float* __restrict__ b_ih,
                       const float* __restrict__ u_c,
                       const float* __restrict__ b_c,
                       const float* __restrict__ w_z,
                       const float* __restrict__ u_z,
                       const float* __restrict__ b_z,
                       float* __restrict__ out,
                       float* __restrict__ ws,
                       int s_lo, int s_hi, int coop)
{
    cg::grid_group grid = cg::this_grid();
    extern __shared__ float lds[];

    float* hm32 = ws;
    float* hj32 = ws + 262144;
    float* ng32 = ws + 524288;

    const int tid  = threadIdx.x;
    const int lane = tid & 63;
    const int wv   = tid >> 6;          // 0..7
    const int tb   = wv & 3;            // b-tile 0..3
    const int hf   = wv >> 2;           // 0: r/c side, 1: z side
    const int r16  = lane & 15;
    const int q4   = (lane >> 4) * 4;
    const int wg   = blockIdx.x;
    const bool isMarg = (wg < 128);

    if (coop) {   // zero t=-1 state (buf 1) of hm and hj
        int gidx = wg * NTHR + tid;     // exactly [0, 131072)
        ws[131072 + gidx] = 0.0f;       // hm32 buf1
        ws[393216 + gidx] = 0.0f;       // hj32 buf1
    }

    if (isMarg) {
        // ============ MARGINAL: block = 16 h-rows x 64 batch ============
        const int c  = wg >> 1;               // 0..63
        const int bh = wg & 1;
        const int g  = c >> 4;
        const int h0 = (c & 15) * 16;
        const int bbo = bh*64 + tb*16 + r16;  // this lane's batch

        const float* wih_g = w_ih + (size_t)g * 768 * 64;
        const float* whh_g = w_hh + (size_t)g * 768 * 256;
        float* wih_s = lds;                   // [48][68], row = gate*16 + (h-h0)
        float* whh_s = lds + MG_WHH;          // [48][260]
        float* exch  = lds + MG_EX;

        // ---- stage weights to LDS once ----
        for (int i = tid; i < 48*64; i += NTHR) {
            int r = i >> 6, k = i & 63;
            int gate = r >> 4, row = r & 15;
            wih_s[r*68 + k] = wih_g[(size_t)(gate*256 + h0 + row)*64 + k];
        }
        for (int i = tid; i < 48*256; i += NTHR) {
            int r = i >> 8, k = i & 255;
            int gate = r >> 4, row = r & 15;
            whh_s[r*260 + k] = whh_g[(size_t)(gate*256 + h0 + row)*256 + k];
        }
        __syncthreads();
        if (coop) grid.sync();

        const int rA = (hf ? 16 : 0);         // LDS gate-block base for accA

        float br_[4], bz_[4], bn_[4];
        #pragma unroll
        for (int r = 0; r < 4; ++r) {
            int hh = h0 + q4 + r;
            br_[r] = b_ih[g*768 + hh];
            bz_[r] = b_ih[g*768 + 256 + hh];
            bn_[r] = b_ih[g*768 + 512 + hh];
        }

        for (int s = s_lo; s <= s_hi; ++s) {
            if (s < Tn) {
                const int p0 = s & 1, p1 = (s+1) & 1;
                float accA[4] = {0.f,0.f,0.f,0.f};   // r (hf0) or z (hf1), full K
                float accB[4] = {0.f,0.f,0.f,0.f};   // i_n (hf0) or h_n (hf1)
                const float* xrow = x + ((size_t)s*128 + bbo)*256 + g*64;
                const float* hrow = hm32 + p1*131072 + bbo*1024 + g*256;

                // x-part K=64
                #pragma unroll 4
                for (int k4 = 0; k4 < 16; ++k4) {
                    float4 xv = *(const float4*)(xrow + k4*4);
                    #pragma unroll
                    for (int r = 0; r < 4; ++r) {
                        float4 wv = *(const float4*)(wih_s + (rA + q4 + r)*68 + k4*4);
                        accA[r] += dot4(wv, xv);
                    }
                    if (hf == 0) {
                        #pragma unroll
                        for (int r = 0; r < 4; ++r) {
                            float4 wn = *(const float4*)(wih_s + (32 + q4 + r)*68 + k4*4);
                            accB[r] += dot4(wn, xv);
                        }
                    }
                }
                // h-part K=256
                #pragma unroll 4
                for (int k4 = 0; k4 < 64; ++k4) {
                    float4 hv = *(const float4*)(hrow + k4*4);
                    #pragma unroll
                    for (int r = 0; r < 4; ++r) {
                        float4 wv = *(const float4*)(whh_s + (rA + q4 + r)*260 + k4*4);
                        accA[r] += dot4(wv, hv);
                    }
                    if (hf == 1) {
                        #pragma unroll
                        for (int r = 0; r < 4; ++r) {
                            float4 wn = *(const float4*)(whh_s + (32 + q4 + r)*260 + k4*4);
                            accB[r] += dot4(wn, hv);
                        }
                    }
                }

                if (hf == 1) {
                    #pragma unroll
                    for (int r = 0; r < 4; ++r) {
                        int idx = (q4 + r)*16 + r16;
                        exch[(tb*2 + 0)*256 + idx] = accA[r];   // z partial
                        exch[(tb*2 + 1)*256 + idx] = accB[r];   // hn partial
                    }
                }
                __syncthreads();
                if (hf == 0) {
                    #pragma unroll
                    for (int r = 0; r < 4; ++r) {
                        int idx = (q4 + r)*16 + r16;
                        int kk  = g*256 + h0 + q4 + r;
                        float zacc  = exch[(tb*2 + 0)*256 + idx];
                        float hnacc = exch[(tb*2 + 1)*256 + idx];
                        float rg = sigf(accA[r] + br_[r]);
                        float zg = sigf(zacc + bz_[r]);
                        float n  = tanhfast(accB[r] + bn_[r] + rg * hnacc);
                        float hmo = hm32[p1*131072 + bbo*1024 + kk];
                        float hnew = n + zg * (hmo - n);
                        hm32[p0*131072 + bbo*1024 + kk] = hnew;
                        ng32[p0*131072 + bbo*1024 + kk] = n;
                    }
                }
                __syncthreads();   // protect exch before next step's writes
            }
            if (coop) grid.sync();
        }
    } else {
        // ============ JOINT: block = 16 j-rows x 64 batch, 1 step behind ====
        const int wg2 = wg - 128;
        const int j0  = (wg2 >> 1) * 16;
        const int bh  = wg2 & 1;
        const int bbo = bh*64 + tb*16 + r16;

        float* uc_s = lds;                    // [16][1028]
        float* uz_s = lds + JT_UZ;            // [16][1028]
        float* wz_s = lds + JT_WZ;            // [16][260]
        float* exch = lds + JT_EX;

        // ---- stage weights to LDS once ----
        for (int i = tid; i < 16*1024; i += NTHR) {
            int r = i >> 10, k = i & 1023;
            uc_s[r*1028 + k] = u_c[(size_t)(j0 + r)*1024 + k];
            uz_s[r*1028 + k] = u_z[(size_t)(j0 + r)*1024 + k];
        }
        for (int i = tid; i < 16*256; i += NTHR) {
            int r = i >> 8, k = i & 255;
            wz_s[r*260 + k] = w_z[(size_t)(j0 + r)*256 + k];
        }
        __syncthreads();
        if (coop) grid.sync();

        float bc_[4], bzj_[4];
        #pragma unroll
        for (int r = 0; r < 4; ++r) {
            int jj = j0 + q4 + r;
            bc_[r]  = b_c[jj];
            bzj_[r] = b_z[jj];
        }

        for (int s = s_lo; s <= s_hi; ++s) {
            if (s >= 1) {
                const int u  = s - 1;
                const int p0 = u & 1, p1 = (u+1) & 1;
                float acc[4] = {0.f,0.f,0.f,0.f};

                if (hf == 0) {
                    // c-part: ng(u) . u_c rows, K=1024
                    const float* ngrow = ng32 + p0*131072 + bbo*1024;
                    #pragma unroll 4
                    for (int k4 = 0; k4 < 256; ++k4) {
                        float4 av = *(const float4*)(ngrow + k4*4);
                        #pragma unroll
                        for (int r = 0; r < 4; ++r) {
                            float4 wv = *(const float4*)(uc_s + (q4 + r)*1028 + k4*4);
                            acc[r] += dot4(wv, av);
                        }
                    }
                } else {
                    // z-part: h_j(u-1) . u_z rows, K=1024
                    const float* hjrow = hj32 + p1*131072 + bbo*1024;
                    #pragma unroll 4
                    for (int k4 = 0; k4 < 256; ++k4) {
                        float4 hv = *(const float4*)(hjrow + k4*4);
                        #pragma unroll
                        for (int r = 0; r < 4; ++r) {
                            float4 wv = *(const float4*)(uz_s + (q4 + r)*1028 + k4*4);
                            acc[r] += dot4(wv, hv);
                        }
                    }
                    // x-part of zj: K=256
                    const float* xrow = x + ((size_t)u*128 + bbo)*256;
                    #pragma unroll 4
                    for (int k4 = 0; k4 < 64; ++k4) {
                        float4 xv = *(const float4*)(xrow + k4*4);
                        #pragma unroll
                        for (int r = 0; r < 4; ++r) {
                            float4 wv = *(const float4*)(wz_s + (q4 + r)*260 + k4*4);
                            acc[r] += dot4(wv, xv);
                        }
                    }
                    #pragma unroll
                    for (int r = 0; r < 4; ++r) {
                        int idx = (q4 + r)*16 + r16;
                        exch[tb*256 + idx] = acc[r];            // zj partial
                    }
                }
                __syncthreads();
                if (hf == 0) {
                    #pragma unroll
                    for (int r = 0; r < 4; ++r) {
                        int idx = (q4 + r)*16 + r16;
                        int jj  = j0 + q4 + r;
                        float zacc = exch[tb*256 + idx];
                        float cg_  = tanhfast(acc[r] + bc_[r]);
                        float zj   = sigf(zacc + bzj_[r]);
                        float hjo  = hj32[p1*131072 + bbo*1024 + jj];
                        float hnew = cg_ + zj * (hjo - cg_);
                        hj32[p0*131072 + bbo*1024 + jj] = hnew;
                        if (u == Tn-1) out[(size_t)bbo*1024 + jj] = hnew;
                    }
                }
                __syncthreads();   // protect exch before next step's writes
            }
            if (coop) grid.sync();
        }
    }
}

extern "C" void kernel_launch(void* const* d_in, const int* in_sizes, int n_in,
                              void* d_out, int out_size, void* d_ws, size_t ws_size,
                              hipStream_t stream) {
    const float* x    = (const float*)d_in[0];
    const float* w_ih = (const float*)d_in[1];
    const float* w_hh = (const float*)d_in[2];
    const float* b_ih = (const float*)d_in[3];
    const float* u_c  = (const float*)d_in[4];
    const float* b_c  = (const float*)d_in[5];
    const float* w_z  = (const float*)d_in[6];
    const float* u_z  = (const float*)d_in[7];
    const float* b_z  = (const float*)d_in[8];
    float* out = (float*)d_out;
    float* ws  = (float*)d_ws;

    (void)hipFuncSetAttribute((const void*)mgrn_k,
                              hipFuncAttributeMaxDynamicSharedMemorySize,
                              LDS_BYTES);

    int s_lo = 0, s_hi = Tn, coop = 1;
    void* args[] = {&x, &w_ih, &w_hh, &b_ih, &u_c, &b_c, &w_z, &u_z, &b_z,
                    &out, &ws, &s_lo, &s_hi, &coop};
    hipError_t e = hipLaunchCooperativeKernel((void*)mgrn_k, dim3(NBLK), dim3(NTHR),
                                              args, LDS_BYTES, stream);
    if (e != hipSuccess) {
        (void)hipGetLastError();   // clear sticky error
        hipMemsetAsync(ws, 0, (size_t)786432 * sizeof(float), stream);
        for (int s = 0; s <= Tn; ++s) {
            mgrn_k<<<dim3(NBLK), dim3(NTHR), LDS_BYTES, stream>>>(
                x, w_ih, w_hh, b_ih, u_c, b_c, w_z, u_z, b_z, out, ws, s, s, 0);
        }
    }
}

// Round 9
// 37995.010 us; speedup vs baseline: 2.1588x; 1.2595x over previous
//
#include <hip/hip_runtime.h>
#include <hip/hip_cooperative_groups.h>

namespace cg = cooperative_groups;

#define Tn 512
#define NBLK 256
#define NTHR 512

// LDS layout (floats), dynamic:
//  JOINT : uc_s [16][1028] @0 ; uz_s [16][1028] @16448 ; wz_s [16][260] @32896 ;
//          exch [2048] @37056  -> total 39104 floats = 156416 B
//  MARG  : wih_s [48][68] @0 ; whh_s [48][260] @3264 ; exch [2048] @15744
#define LDS_BYTES 156416
#define JT_UZ 16448
#define JT_WZ 32896
#define JT_EX 37056
#define MG_WHH 3264
#define MG_EX 15744

__device__ __forceinline__ float sigf(float v){ return 1.0f/(1.0f+__expf(-v)); }
__device__ __forceinline__ float tanhfast(float v){
    float ax=fabsf(v); float e=__expf(-2.0f*ax);
    float t=(1.0f-e)/(1.0f+e); return copysignf(t,v);
}
__device__ __forceinline__ float dot4(float4 a, float4 b){
    return a.x*b.x + a.y*b.y + a.z*b.z + a.w*b.w;
}

// ---- point-to-point sync flags (persist across replays; zeroed each call) ----
__device__ int d_mgrp[2][4][513];   // marg blocks done step s, per (bh, g): target 16
__device__ int d_jflag[2][513];     // joint blocks done step u, per bh: target 64

__device__ __forceinline__ void spin_ge(int* p, int target){
    while (__hip_atomic_load(p, __ATOMIC_RELAXED, __HIP_MEMORY_SCOPE_AGENT) < target)
        __builtin_amdgcn_s_sleep(1);
}

// ws layout (float offsets) — proven 786432-float footprint:
//   hm32 : 2 x [128][1024] f32 @ 0        (h_m, [b][g*256+h], buf p = p*131072)
//   hj32 : 2 x [128][1024] f32 @ 262144   (h_j, [b][j])
//   ng32 : 2 x [128][1024] f32 @ 524288   (newgates, [b][g*256+h])
// state(t) in buf t&1 ; t=-1 zeros live in buf 1.
// Buffer-recycle safety: marg step s overwrites ng(s-2) => gated on jflag[s-2];
// hm/hj recycling is gated by the sibling-group flags (see spin conditions).

__launch_bounds__(NTHR, 2)
__global__ void mgrn_k(const float* __restrict__ x,
                       const float* __restrict__ w_ih,
                       const float* __restrict__ w_hh,
                       const float* __restrict__ b_ih,
                       const float* __restrict__ u_c,
                       const float* __restrict__ b_c,
                       const float* __restrict__ w_z,
                       const float* __restrict__ u_z,
                       const float* __restrict__ b_z,
                       float* __restrict__ out,
                       float* __restrict__ ws,
                       int s_lo, int s_hi, int coop)
{
    cg::grid_group grid = cg::this_grid();
    extern __shared__ float lds[];

    float* hm32 = ws;
    float* hj32 = ws + 262144;
    float* ng32 = ws + 524288;

    const int tid  = threadIdx.x;
    const int lane = tid & 63;
    const int wv   = tid >> 6;          // 0..7
    const int tb   = wv & 3;            // b-tile 0..3
    const int hf   = wv >> 2;           // 0: r/c side, 1: z side
    const int r16  = lane & 15;
    const int q4   = (lane >> 4) * 4;
    const int wg   = blockIdx.x;
    const bool isMarg = (wg < 128);

    if (coop) {   // zero t=-1 state (buf 1) of hm and hj + sync flags
        int gidx = wg * NTHR + tid;     // exactly [0, 131072)
        ws[131072 + gidx] = 0.0f;       // hm32 buf1
        ws[393216 + gidx] = 0.0f;       // hj32 buf1
        int* fm = &d_mgrp[0][0][0];
        if (gidx < 2*4*513) fm[gidx] = 0;
        int* fj = &d_jflag[0][0];
        if (gidx < 2*513) fj[gidx] = 0;
    }

    if (isMarg) {
        // ============ MARGINAL: block = 16 h-rows x 64 batch ============
        const int c  = wg >> 1;               // 0..63
        const int bh = wg & 1;
        const int g  = c >> 4;
        const int h0 = (c & 15) * 16;
        const int bbo = bh*64 + tb*16 + r16;  // this lane's batch

        const float* wih_g = w_ih + (size_t)g * 768 * 64;
        const float* whh_g = w_hh + (size_t)g * 768 * 256;
        float* wih_s = lds;                   // [48][68], row = gate*16 + (h-h0)
        float* whh_s = lds + MG_WHH;          // [48][260]
        float* exch  = lds + MG_EX;

        // ---- stage weights to LDS once ----
        for (int i = tid; i < 48*64; i += NTHR) {
            int r = i >> 6, k = i & 63;
            int gate = r >> 4, row = r & 15;
            wih_s[r*68 + k] = wih_g[(size_t)(gate*256 + h0 + row)*64 + k];
        }
        for (int i = tid; i < 48*256; i += NTHR) {
            int r = i >> 8, k = i & 255;
            int gate = r >> 4, row = r & 15;
            whh_s[r*260 + k] = whh_g[(size_t)(gate*256 + h0 + row)*256 + k];
        }
        __syncthreads();
        if (coop) grid.sync();   // flags + zero-state globally visible

        const int rA = (hf ? 16 : 0);         // LDS gate-block base for accA

        float br_[4], bz_[4], bn_[4];
        #pragma unroll
        for (int r = 0; r < 4; ++r) {
            int hh = h0 + q4 + r;
            br_[r] = b_ih[g*768 + hh];
            bz_[r] = b_ih[g*768 + 256 + hh];
            bn_[r] = b_ih[g*768 + 512 + hh];
        }

        for (int s = s_lo; s <= s_hi; ++s) {
            if (s < Tn) {
                const int p0 = s & 1, p1 = (s+1) & 1;
                float accA[4] = {0.f,0.f,0.f,0.f};   // r (hf0) or z (hf1), full K
                float accB[4] = {0.f,0.f,0.f,0.f};   // i_n (hf0) or h_n (hf1)
                const float* xrow = x + ((size_t)s*128 + bbo)*256 + g*64;

                // ---- x-part K=64 (recurrence-independent: before the spin) ----
                #pragma unroll 4
                for (int k4 = 0; k4 < 16; ++k4) {
                    float4 xv = *(const float4*)(xrow + k4*4);
                    #pragma unroll
                    for (int r = 0; r < 4; ++r) {
                        float4 wv = *(const float4*)(wih_s + (rA + q4 + r)*68 + k4*4);
                        accA[r] += dot4(wv, xv);
                    }
                    if (hf == 0) {
                        #pragma unroll
                        for (int r = 0; r < 4; ++r) {
                            float4 wn = *(const float4*)(wih_s + (32 + q4 + r)*68 + k4*4);
                            accB[r] += dot4(wn, xv);
                        }
                    }
                }

                // ---- wait: hm(s-1) from sibling group; ng(s-2) consumed ----
                if (coop) {
                    if (tid == 0) {
                        if (s >= 1) spin_ge(&d_mgrp[bh][g][s-1], 16);
                        if (s >= 2) spin_ge(&d_jflag[bh][s-2], 64);
                        __threadfence();   // acquire: invalidate L1/L2 for fresh state
                    }
                    __syncthreads();
                }

                const float* hrow = hm32 + p1*131072 + bbo*1024 + g*256;
                // ---- h-part K=256 ----
                #pragma unroll 4
                for (int k4 = 0; k4 < 64; ++k4) {
                    float4 hv = *(const float4*)(hrow + k4*4);
                    #pragma unroll
                    for (int r = 0; r < 4; ++r) {
                        float4 wv = *(const float4*)(whh_s + (rA + q4 + r)*260 + k4*4);
                        accA[r] += dot4(wv, hv);
                    }
                    if (hf == 1) {
                        #pragma unroll
                        for (int r = 0; r < 4; ++r) {
                            float4 wn = *(const float4*)(whh_s + (32 + q4 + r)*260 + k4*4);
                            accB[r] += dot4(wn, hv);
                        }
                    }
                }

                if (hf == 1) {
                    #pragma unroll
                    for (int r = 0; r < 4; ++r) {
                        int idx = (q4 + r)*16 + r16;
                        exch[(tb*2 + 0)*256 + idx] = accA[r];   // z partial
                        exch[(tb*2 + 1)*256 + idx] = accB[r];   // hn partial
                    }
                }
                __syncthreads();
                if (hf == 0) {
                    #pragma unroll
                    for (int r = 0; r < 4; ++r) {
                        int idx = (q4 + r)*16 + r16;
                        int kk  = g*256 + h0 + q4 + r;
                        float zacc  = exch[(tb*2 + 0)*256 + idx];
                        float hnacc = exch[(tb*2 + 1)*256 + idx];
                        float rg = sigf(accA[r] + br_[r]);
                        float zg = sigf(zacc + bz_[r]);
                        float n  = tanhfast(accB[r] + bn_[r] + rg * hnacc);
                        float hmo = hm32[p1*131072 + bbo*1024 + kk];
                        float hnew = n + zg * (hmo - n);
                        hm32[p0*131072 + bbo*1024 + kk] = hnew;
                        ng32[p0*131072 + bbo*1024 + kk] = n;
                    }
                }
                // barrier drains all stores (compiler emits vmcnt(0) before s_barrier),
                // then tid0's threadfence (wbl2) publishes them device-wide.
                __syncthreads();
                if (coop && tid == 0) {
                    __threadfence();
                    atomicAdd(&d_mgrp[bh][g][s], 1);
                }
            }
        }
    } else {
        // ============ JOINT: block = 16 j-rows x 64 batch, 1 step behind ====
        const int wg2 = wg - 128;
        const int j0  = (wg2 >> 1) * 16;
        const int bh  = wg2 & 1;
        const int bbo = bh*64 + tb*16 + r16;

        float* uc_s = lds;                    // [16][1028]
        float* uz_s = lds + JT_UZ;            // [16][1028]
        float* wz_s = lds + JT_WZ;            // [16][260]
        float* exch = lds + JT_EX;

        // ---- stage weights to LDS once ----
        for (int i = tid; i < 16*1024; i += NTHR) {
            int r = i >> 10, k = i & 1023;
            uc_s[r*1028 + k] = u_c[(size_t)(j0 + r)*1024 + k];
            uz_s[r*1028 + k] = u_z[(size_t)(j0 + r)*1024 + k];
        }
        for (int i = tid; i < 16*256; i += NTHR) {
            int r = i >> 8, k = i & 255;
            wz_s[r*260 + k] = w_z[(size_t)(j0 + r)*256 + k];
        }
        __syncthreads();
        if (coop) grid.sync();   // flags + zero-state globally visible

        float bc_[4], bzj_[4];
        #pragma unroll
        for (int r = 0; r < 4; ++r) {
            int jj = j0 + q4 + r;
            bc_[r]  = b_c[jj];
            bzj_[r] = b_z[jj];
        }

        for (int s = s_lo; s <= s_hi; ++s) {
            if (s >= 1) {
                const int u  = s - 1;
                const int p0 = u & 1, p1 = (u+1) & 1;
                float acc[4] = {0.f,0.f,0.f,0.f};

                // ---- z x-part K=256 (recurrence-independent: before the spin) ----
                if (hf == 1) {
                    const float* xrow = x + ((size_t)u*128 + bbo)*256;
                    #pragma unroll 4
                    for (int k4 = 0; k4 < 64; ++k4) {
                        float4 xv = *(const float4*)(xrow + k4*4);
                        #pragma unroll
                        for (int r = 0; r < 4; ++r) {
                            float4 wv = *(const float4*)(wz_s + (q4 + r)*260 + k4*4);
                            acc[r] += dot4(wv, xv);
                        }
                    }
                }

                // ---- wait: ng(u) from all marg groups; hj(u-1) from joint peers ----
                if (coop) {
                    if (tid == 0) {
                        spin_ge(&d_mgrp[bh][0][u], 16);
                        spin_ge(&d_mgrp[bh][1][u], 16);
                        spin_ge(&d_mgrp[bh][2][u], 16);
                        spin_ge(&d_mgrp[bh][3][u], 16);
                        if (u >= 1) spin_ge(&d_jflag[bh][u-1], 64);
                        __threadfence();   // acquire: invalidate for fresh state
                    }
                    __syncthreads();
                }

                if (hf == 0) {
                    // c-part: ng(u) . u_c rows, K=1024
                    const float* ngrow = ng32 + p0*131072 + bbo*1024;
                    #pragma unroll 4
                    for (int k4 = 0; k4 < 256; ++k4) {
                        float4 av = *(const float4*)(ngrow + k4*4);
                        #pragma unroll
                        for (int r = 0; r < 4; ++r) {
                            float4 wv = *(const float4*)(uc_s + (q4 + r)*1028 + k4*4);
                            acc[r] += dot4(wv, av);
                        }
                    }
                } else {
                    // z-part: h_j(u-1) . u_z rows, K=1024
                    const float* hjrow = hj32 + p1*131072 + bbo*1024;
                    #pragma unroll 4
                    for (int k4 = 0; k4 < 256; ++k4) {
                        float4 hv = *(const float4*)(hjrow + k4*4);
                        #pragma unroll
                        for (int r = 0; r < 4; ++r) {
                            float4 wv = *(const float4*)(uz_s + (q4 + r)*1028 + k4*4);
                            acc[r] += dot4(wv, hv);
                        }
                    }
                    #pragma unroll
                    for (int r = 0; r < 4; ++r) {
                        int idx = (q4 + r)*16 + r16;
                        exch[tb*256 + idx] = acc[r];            // zj partial
                    }
                }
                __syncthreads();
                if (hf == 0) {
                    #pragma unroll
                    for (int r = 0; r < 4; ++r) {
                        int idx = (q4 + r)*16 + r16;
                        int jj  = j0 + q4 + r;
                        float zacc = exch[tb*256 + idx];
                        float cg_  = tanhfast(acc[r] + bc_[r]);
                        float zj   = sigf(zacc + bzj_[r]);
                        float hjo  = hj32[p1*131072 + bbo*1024 + jj];
                        float hnew = cg_ + zj * (hjo - cg_);
                        hj32[p0*131072 + bbo*1024 + jj] = hnew;
                        if (u == Tn-1) out[(size_t)bbo*1024 + jj] = hnew;
                    }
                }
                __syncthreads();
                if (coop && tid == 0) {
                    __threadfence();
                    atomicAdd(&d_jflag[bh][u], 1);
                }
            }
        }
    }
}

extern "C" void kernel_launch(void* const* d_in, const int* in_sizes, int n_in,
                              void* d_out, int out_size, void* d_ws, size_t ws_size,
                              hipStream_t stream) {
    const float* x    = (const float*)d_in[0];
    const float* w_ih = (const float*)d_in[1];
    const float* w_hh = (const float*)d_in[2];
    const float* b_ih = (const float*)d_in[3];
    const float* u_c  = (const float*)d_in[4];
    const float* b_c  = (const float*)d_in[5];
    const float* w_z  = (const float*)d_in[6];
    const float* u_z  = (const float*)d_in[7];
    const float* b_z  = (const float*)d_in[8];
    float* out = (float*)d_out;
    float* ws  = (float*)d_ws;

    (void)hipFuncSetAttribute((const void*)mgrn_k,
                              hipFuncAttributeMaxDynamicSharedMemorySize,
                              LDS_BYTES);

    int s_lo = 0, s_hi = Tn, coop = 1;
    void* args[] = {&x, &w_ih, &w_hh, &b_ih, &u_c, &b_c, &w_z, &u_z, &b_z,
                    &out, &ws, &s_lo, &s_hi, &coop};
    hipError_t e = hipLaunchCooperativeKernel((void*)mgrn_k, dim3(NBLK), dim3(NTHR),
                                              args, LDS_BYTES, stream);
    if (e != hipSuccess) {
        (void)hipGetLastError();   // clear sticky error
        hipMemsetAsync(ws, 0, (size_t)786432 * sizeof(float), stream);
        for (int s = 0; s <= Tn; ++s) {
            mgrn_k<<<dim3(NBLK), dim3(NTHR), LDS_BYTES, stream>>>(
                x, w_ih, w_hh, b_ih, u_c, b_c, w_z, u_z, b_z, out, ws, s, s, 0);
        }
    }
}